// Round 13
// baseline (1485.525 us; speedup 1.0000x reference)
//
#include <hip/hip_runtime.h>
#include <hip/hip_fp16.h>

typedef _Float16 f16;
typedef _Float16 f16x8 __attribute__((ext_vector_type(8)));
typedef _Float16 f16x4 __attribute__((ext_vector_type(4)));
typedef float f32x4v __attribute__((ext_vector_type(4)));
typedef unsigned long long u64;

#define S_LEN 1024
#define NS 512
#define NV 32000
#define NW 4          // scan workers (CUs); each owns 128 n-columns
#define SENT 0x7C007C007C007C00ULL   // 4x f16 +inf: unreachable for tanh output
#define FUSED_LDS 98304              // >80KB -> exactly 1 block/CU

#define MFMA16(a, b, c) __builtin_amdgcn_mfma_f32_16x16x32_f16((a), (b), (c), 0, 0, 0)

#define XLD(p) __hip_atomic_load((p), __ATOMIC_RELAXED, __HIP_MEMORY_SCOPE_AGENT)

// ---------------------------------------------------------------------------
// ws layout:
//   u16   : [1024][512][4] f16  at 0      (4 MB)   u[s][n][b]  (batch-packed)
//   X     : u64[1024][512]      at 4 MB   (4 MB)   state record + exchange
//   bT16  : [512][512]     f16  at 8 MB   (512 KB)
// ---------------------------------------------------------------------------

// transpose b -> f16, and refill X with sentinel (every launch; graph-safe)
__global__ __launch_bounds__(256) void transpose512_f16_kernel(
        const float* __restrict__ src, f16* __restrict__ dstT,
        u64* __restrict__ X) {
    int idx = blockIdx.x * 256 + threadIdx.x;   // 0..262143
    X[idx] = SENT;
    X[idx + 262144] = SENT;
    int r = idx >> 9;
    int c = idx & 511;
    dstT[c * 512 + r] = (f16)src[idx];
}

// ---------------------------------------------------------------------------
// embed + input projection: u[m][n] = sum_e emb[x[m]][e] * b[e][n], m = s*4+b
// ---------------------------------------------------------------------------
__global__ __launch_bounds__(256) void embu_kernel(
        const int* __restrict__ x, const float* __restrict__ emb,
        const f16* __restrict__ bT, f16* __restrict__ u16) {
    __shared__ f16 embA[64 * 40];
    __shared__ f16 Bt[512 * 40];
    __shared__ int xi[64];

    int t = threadIdx.x;
    int wg = blockIdx.x;
    if (t < 64) {
        int m = wg * 64 + t;
        int bb = m & 3, ss = m >> 2;
        xi[t] = x[bb * S_LEN + ss];
    }
    __syncthreads();

    int wv = t >> 6, l = t & 63, lr = l & 15, lg = l >> 4;

    f32x4v acc[32];
#pragma unroll
    for (int i = 0; i < 32; i++) acc[i] = (f32x4v){0.f, 0.f, 0.f, 0.f};

    for (int kc = 0; kc < 512; kc += 32) {
        __syncthreads();
        {
            int tk = t >> 2, c0 = (t & 3) * 8;
            const float* src = emb + (size_t)xi[tk] * NS + kc + c0;
            float4 v0 = *(const float4*)src;
            float4 v1 = *(const float4*)(src + 4);
            f16x8 h;
            h[0] = (f16)v0.x; h[1] = (f16)v0.y; h[2] = (f16)v0.z; h[3] = (f16)v0.w;
            h[4] = (f16)v1.x; h[5] = (f16)v1.y; h[6] = (f16)v1.z; h[7] = (f16)v1.w;
            *(f16x8*)&embA[tk * 40 + c0] = h;
        }
        {
            int c0 = (t & 3) * 8;
            int n0 = t >> 2;
#pragma unroll
            for (int rr = 0; rr < 8; rr++) {
                int n = rr * 64 + n0;
                f16x8 v = *(const f16x8*)&bT[n * 512 + kc + c0];
                *(f16x8*)&Bt[n * 40 + c0] = v;
            }
        }
        __syncthreads();

        f16x8 af = *(const f16x8*)&embA[(wv * 16 + lr) * 40 + 8 * lg];
#pragma unroll
        for (int vt = 0; vt < 32; vt++) {
            f16x8 bf = *(const f16x8*)&Bt[(vt * 16 + lr) * 40 + 8 * lg];
            acc[vt] = MFMA16(af, bf, acc[vt]);
        }
    }

    int m0 = wg * 64 + wv * 16 + 4 * lg;
    int ss = m0 >> 2;
#pragma unroll
    for (int vt = 0; vt < 32; vt++) {
        int n = vt * 16 + lr;
        f16x4 h;
#pragma unroll
        for (int i = 0; i < 4; i++) h[i] = (f16)acc[vt][i];
        *(f16x4*)&u16[((size_t)ss * NS + n) * 4] = h;
    }
}

// ---------------------------------------------------------------------------
// FUSED scan + readout.
//   blocks 0..3    : scan, R7 structure (8 waves compute, waves 0-5 also
//                    gather inline) + 4-deep rotating poll (RTT/4 sampling).
//   blocks 4..4003 : readout tiles; canary gate; A staged from X (plain
//                    loads + agent fallback); XOR-swizzled LDS (0 conflicts).
// 96 KB dynamic LDS -> 1 block/CU.
// ---------------------------------------------------------------------------
__global__ __launch_bounds__(512) void fused_kernel(
        const float* __restrict__ a, const f16* __restrict__ u16,
        const float* __restrict__ cw, const float* __restrict__ cb,
        u64* __restrict__ X, float* __restrict__ out) {
    extern __shared__ char smem[];
    int t = threadIdx.x;
    int bid = blockIdx.x;
    int w = t >> 6, l = t & 63, lr = l & 15, lg = l >> 4;

    if (bid < NW) {
        // ================= scan =================
        f16* Sb = (f16*)smem;               // [2][4][544] f16
        int r = bid;
        int col = r * 128 + w * 16 + lr;

        int gcol = -1;
        if (w < 6) {
            int cwk = w + (w >= 2 * r ? 2 : 0);   // skip own chunks {2r,2r+1}
            gcol = cwk * 64 + l;
        }

        for (int i = t; i < 2 * 4 * 544; i += 512) Sb[i] = (f16)0.f;

        // stationary A fragments (64 VGPR/lane)
        f16x8 afr[16];
#pragma unroll
        for (int ks = 0; ks < 16; ks++) {
            f16x8 h;
#pragma unroll
            for (int j = 0; j < 8; j++)
                h[j] = (f16)a[(size_t)(ks * 32 + 8 * lg + j) * NS + col];
            afr[ks] = h;
        }

        f16x4 upf = *(const f16x4*)&u16[(size_t)col * 4];

        __syncthreads();

#pragma unroll 1
        for (int s = 0; s < S_LEN; s++) {
            int cur = s & 1, nxt = cur ^ 1;

            f32x4v acca, accb;
            acca[0] = (float)upf[0]; acca[1] = (float)upf[1];
            acca[2] = (float)upf[2]; acca[3] = (float)upf[3];
            accb = (f32x4v){0.f, 0.f, 0.f, 0.f};

            {
                int sn = (s + 1 < S_LEN) ? s + 1 : S_LEN - 1;
                upf = *(const f16x4*)&u16[((size_t)sn * NS + col) * 4];
            }

            const char* sb = (const char*)Sb + cur * 4352 +
                             (lr & 3) * 1088 + lg * 16;
#pragma unroll
            for (int ks = 0; ks < 16; ks += 2) {
                f16x8 s0 = *(const f16x8*)(sb + ks * 64);
                f16x8 s1 = *(const f16x8*)(sb + ks * 64 + 64);
                acca = MFMA16(s0, afr[ks], acca);
                accb = MFMA16(s1, afr[ks + 1], accb);
            }

            // tanh + publish: X store first (fire-and-forget), then LDS
            if (lg == 0) {
                union { u64 u; f16 h[4]; } pk;
#pragma unroll
                for (int i = 0; i < 4; i++) {
                    float y = acca[i] + accb[i];
                    float e = __expf(2.0f * y);
                    float rc = __builtin_amdgcn_rcpf(e + 1.0f);
                    y = __builtin_fmaf(-2.0f, rc, 1.0f);   // tanh
                    pk.h[i] = (f16)y;
                }
                __hip_atomic_store(&X[(size_t)s * NS + col], pk.u,
                                   __ATOMIC_RELAXED, __HIP_MEMORY_SCOPE_AGENT);
#pragma unroll
                for (int i = 0; i < 4; i++)
                    Sb[nxt * 2176 + i * 544 + col] = pk.h[i];
            }

            if (s == S_LEN - 1) break;

            // inline gather, 4-deep rotating poll: sampling interval ~RTT/4
            if (w < 6) {
                const u64* p = &X[(size_t)s * NS + gcol];
                u64 v;
                u64 a0 = XLD(p), a1 = XLD(p), a2 = XLD(p), a3 = XLD(p);
                for (;;) {
                    if (a0 != SENT) { v = a0; break; }
                    a0 = XLD(p);
                    if (a1 != SENT) { v = a1; break; }
                    a1 = XLD(p);
                    if (a2 != SENT) { v = a2; break; }
                    a2 = XLD(p);
                    if (a3 != SENT) { v = a3; break; }
                    a3 = XLD(p);
                }
                union { u64 u; f16 h[4]; } pk;
                pk.u = v;
#pragma unroll
                for (int i = 0; i < 4; i++)
                    Sb[nxt * 2176 + i * 544 + gcol] = pk.h[i];
            }

            asm volatile("s_waitcnt lgkmcnt(0)" ::: "memory");
            __builtin_amdgcn_s_barrier();
            __builtin_amdgcn_sched_barrier(0);
        }
        return;
    }

    // ================= readout =================
    // XOR-swizzled LDS tiles: row stride 64 f16 (128 B), byte ^= (row&7)<<4
    char* AstB = smem;                   // [256][64] f16
    char* BwB  = smem + 256 * 64 * 2;    // [128][64] f16

    int idx = bid - NW;
    int bm = idx / 250;      // bm-major: early blocks handle early s
    int bn = idx % 250;
    int s0 = bm * 64;

    if (t == 0) {
        int sc = s0 + 56;    // canary; per-element polls below are airtight
        while (XLD(&X[(size_t)sc * NS]) == SENT)
            __builtin_amdgcn_s_sleep(16);
    }
    __syncthreads();

    int wr = w >> 1, wc = w & 1;

    f32x4v acc[4][4];
#pragma unroll
    for (int i = 0; i < 4; i++)
#pragma unroll
        for (int j = 0; j < 4; j++) acc[i][j] = (f32x4v){0.f, 0.f, 0.f, 0.f};

    for (int kc = 0; kc < 512; kc += 64) {
        __syncthreads();
        // stage A from X: plain loads, agent fallback on sentinel,
        // in-register 4x8 transpose -> 4 swizzled b128 writes
        {
            int srel = t >> 3;
            int ck = (t & 7) * 8;
            const u64* xs = &X[(size_t)(s0 + srel) * NS + kc + ck];
            u64 v[8];
#pragma unroll
            for (int j = 0; j < 8; j++) v[j] = xs[j];   // L2-cacheable
#pragma unroll
            for (int j = 0; j < 8; j++)
                while (v[j] == SENT) v[j] = XLD(&xs[j]);
#pragma unroll
            for (int b = 0; b < 4; b++) {
                f16x8 row;
#pragma unroll
                for (int j = 0; j < 8; j++) {
                    union { u64 u; f16 h[4]; } pk;
                    pk.u = v[j];
                    row[j] = pk.h[b];
                }
                int rr = srel * 4 + b;
                int byte = (rr * 128 + ck * 2) ^ ((rr & 7) << 4);
                *(f16x8*)(AstB + byte) = row;
            }
        }
        // stage B: c_w fp32 -> f16, swizzled 8B writes
#pragma unroll
        for (int q = 0; q < 4; q++) {
            int i2 = q * 512 + t;
            int row = i2 >> 4;
            int c0 = (i2 & 15) * 4;
            float4 v = *(const float4*)&cw[(size_t)(bn * 128 + row) * NS + kc + c0];
            f16x4 h;
            h[0] = (f16)v.x; h[1] = (f16)v.y; h[2] = (f16)v.z; h[3] = (f16)v.w;
            int byte = (row * 128 + c0 * 2) ^ ((row & 7) << 4);
            *(f16x4*)(BwB + byte) = h;
        }
        __syncthreads();

#pragma unroll
        for (int ks = 0; ks < 2; ks++) {
            f16x8 af[4], bf[4];
#pragma unroll
            for (int mt = 0; mt < 4; mt++) {
                int rr = wr * 64 + mt * 16 + lr;
                int byte = (rr * 128 + ks * 64 + lg * 16) ^ ((lr & 7) << 4);
                af[mt] = *(const f16x8*)(AstB + byte);
            }
#pragma unroll
            for (int vt = 0; vt < 4; vt++) {
                int rr = wc * 64 + vt * 16 + lr;
                int byte = (rr * 128 + ks * 64 + lg * 16) ^ ((lr & 7) << 4);
                bf[vt] = *(const f16x8*)(BwB + byte);
            }
#pragma unroll
            for (int mt = 0; mt < 4; mt++)
#pragma unroll
                for (int vt = 0; vt < 4; vt++)
                    acc[mt][vt] = MFMA16(af[mt], bf[vt], acc[mt][vt]);
        }
    }

    float bias[4];
#pragma unroll
    for (int vt = 0; vt < 4; vt++)
        bias[vt] = cb[bn * 128 + wc * 64 + vt * 16 + lr];

#pragma unroll
    for (int mt = 0; mt < 4; mt++) {
#pragma unroll
        for (int i = 0; i < 4; i++) {
            int m = bm * 256 + wr * 64 + mt * 16 + 4 * lg + i;
            int bb = m & 3, ss = m >> 2;
            float* orow = out + (size_t)(bb * S_LEN + ss) * NV + bn * 128 + wc * 64;
#pragma unroll
            for (int vt = 0; vt < 4; vt++)
                orow[vt * 16 + lr] = acc[mt][vt][i] + bias[vt];
        }
    }
}

// ---------------------------------------------------------------------------
extern "C" void kernel_launch(void* const* d_in, const int* in_sizes, int n_in,
                              void* d_out, int out_size, void* d_ws, size_t ws_size,
                              hipStream_t stream) {
    (void)in_sizes; (void)n_in; (void)out_size; (void)ws_size;

    const int*   x   = (const int*)d_in[0];
    const float* emb = (const float*)d_in[1];
    const float* a   = (const float*)d_in[2];
    const float* bm  = (const float*)d_in[3];
    const float* cw  = (const float*)d_in[4];
    const float* cb  = (const float*)d_in[5];
    float* out = (float*)d_out;

    char* ws = (char*)d_ws;
    f16* u16 = (f16*)(ws);
    u64* X   = (u64*)(ws + (4u << 20));
    f16* bT16 = (f16*)(ws + (8u << 20));

    hipFuncSetAttribute(reinterpret_cast<const void*>(fused_kernel),
                        hipFuncAttributeMaxDynamicSharedMemorySize,
                        FUSED_LDS);

    transpose512_f16_kernel<<<1024, 256, 0, stream>>>(bm, bT16, X);
    embu_kernel<<<64, 256, 0, stream>>>(x, emb, bT16, u16);
    fused_kernel<<<NW + 16 * 250, 512, FUSED_LDS, stream>>>(
        a, u16, cw, cb, X, out);
}

// Round 14
// 1357.827 us; speedup vs baseline: 1.0940x; 1.0940x over previous
//
#include <hip/hip_runtime.h>
#include <hip/hip_fp16.h>

typedef _Float16 f16;
typedef _Float16 f16x8 __attribute__((ext_vector_type(8)));
typedef _Float16 f16x4 __attribute__((ext_vector_type(4)));
typedef float f32x4v __attribute__((ext_vector_type(4)));
typedef unsigned long long u64;

#define S_LEN 1024
#define NS 512
#define NV 32000
#define NW 4          // scan workers (CUs); each owns 128 n-columns
#define SENT 0x7C007C007C007C00ULL   // 4x f16 +inf: unreachable for tanh output
#define FUSED_LDS 98304              // >80KB -> exactly 1 block/CU

#define MFMA16(a, b, c) __builtin_amdgcn_mfma_f32_16x16x32_f16((a), (b), (c), 0, 0, 0)

#define XLD(p) __hip_atomic_load((p), __ATOMIC_RELAXED, __HIP_MEMORY_SCOPE_AGENT)

// ---------------------------------------------------------------------------
// ws layout:
//   u16   : [1024][512][4] f16  at 0      (4 MB)   u[s][n][b]  (batch-packed)
//   X     : u64[1024][512]      at 4 MB   (4 MB)   state record + exchange
//   bT16  : [512][512]     f16  at 8 MB   (512 KB)
// ---------------------------------------------------------------------------

// transpose b -> f16, and refill X with sentinel (every launch; graph-safe)
__global__ __launch_bounds__(256) void transpose512_f16_kernel(
        const float* __restrict__ src, f16* __restrict__ dstT,
        u64* __restrict__ X) {
    int idx = blockIdx.x * 256 + threadIdx.x;   // 0..262143
    X[idx] = SENT;
    X[idx + 262144] = SENT;
    int r = idx >> 9;
    int c = idx & 511;
    dstT[c * 512 + r] = (f16)src[idx];
}

// ---------------------------------------------------------------------------
// embed + input projection: u[m][n] = sum_e emb[x[m]][e] * b[e][n], m = s*4+b
// ---------------------------------------------------------------------------
__global__ __launch_bounds__(256) void embu_kernel(
        const int* __restrict__ x, const float* __restrict__ emb,
        const f16* __restrict__ bT, f16* __restrict__ u16) {
    __shared__ f16 embA[64 * 40];
    __shared__ f16 Bt[512 * 40];
    __shared__ int xi[64];

    int t = threadIdx.x;
    int wg = blockIdx.x;
    if (t < 64) {
        int m = wg * 64 + t;
        int bb = m & 3, ss = m >> 2;
        xi[t] = x[bb * S_LEN + ss];
    }
    __syncthreads();

    int wv = t >> 6, l = t & 63, lr = l & 15, lg = l >> 4;

    f32x4v acc[32];
#pragma unroll
    for (int i = 0; i < 32; i++) acc[i] = (f32x4v){0.f, 0.f, 0.f, 0.f};

    for (int kc = 0; kc < 512; kc += 32) {
        __syncthreads();
        {
            int tk = t >> 2, c0 = (t & 3) * 8;
            const float* src = emb + (size_t)xi[tk] * NS + kc + c0;
            float4 v0 = *(const float4*)src;
            float4 v1 = *(const float4*)(src + 4);
            f16x8 h;
            h[0] = (f16)v0.x; h[1] = (f16)v0.y; h[2] = (f16)v0.z; h[3] = (f16)v0.w;
            h[4] = (f16)v1.x; h[5] = (f16)v1.y; h[6] = (f16)v1.z; h[7] = (f16)v1.w;
            *(f16x8*)&embA[tk * 40 + c0] = h;
        }
        {
            int c0 = (t & 3) * 8;
            int n0 = t >> 2;
#pragma unroll
            for (int rr = 0; rr < 8; rr++) {
                int n = rr * 64 + n0;
                f16x8 v = *(const f16x8*)&bT[n * 512 + kc + c0];
                *(f16x8*)&Bt[n * 40 + c0] = v;
            }
        }
        __syncthreads();

        f16x8 af = *(const f16x8*)&embA[(wv * 16 + lr) * 40 + 8 * lg];
#pragma unroll
        for (int vt = 0; vt < 32; vt++) {
            f16x8 bf = *(const f16x8*)&Bt[(vt * 16 + lr) * 40 + 8 * lg];
            acc[vt] = MFMA16(af, bf, acc[vt]);
        }
    }

    int m0 = wg * 64 + wv * 16 + 4 * lg;
    int ss = m0 >> 2;
#pragma unroll
    for (int vt = 0; vt < 32; vt++) {
        int n = vt * 16 + lr;
        f16x4 h;
#pragma unroll
        for (int i = 0; i < 4; i++) h[i] = (f16)acc[vt][i];
        *(f16x4*)&u16[((size_t)ss * NS + n) * 4] = h;
    }
}

// ---------------------------------------------------------------------------
// FUSED scan + readout.
//   blocks 0..3    : scan, R7/R11 structure verbatim: 8 waves compute 16 cols
//                    each; waves 0-5 also gather one remote 64-col chunk via
//                    simple do-while data-poll; one barrier per step.
//   blocks 4..4003 : readout tiles; canary gate; A staged from X (plain
//                    loads + agent fallback); XOR-swizzled LDS (0 conflicts).
// 96 KB dynamic LDS -> 1 block/CU.
// ---------------------------------------------------------------------------
__global__ __launch_bounds__(512) void fused_kernel(
        const float* __restrict__ a, const f16* __restrict__ u16,
        const float* __restrict__ cw, const float* __restrict__ cb,
        u64* __restrict__ X, float* __restrict__ out) {
    extern __shared__ char smem[];
    int t = threadIdx.x;
    int bid = blockIdx.x;
    int w = t >> 6, l = t & 63, lr = l & 15, lg = l >> 4;

    if (bid < NW) {
        // ================= scan =================
        f16* Sb = (f16*)smem;               // [2][4][544] f16
        int r = bid;
        int col = r * 128 + w * 16 + lr;

        int gcol = -1;
        if (w < 6) {
            int cwk = w + (w >= 2 * r ? 2 : 0);   // skip own chunks {2r,2r+1}
            gcol = cwk * 64 + l;
        }

        for (int i = t; i < 2 * 4 * 544; i += 512) Sb[i] = (f16)0.f;

        // stationary A fragments (64 VGPR/lane)
        f16x8 afr[16];
#pragma unroll
        for (int ks = 0; ks < 16; ks++) {
            f16x8 h;
#pragma unroll
            for (int j = 0; j < 8; j++)
                h[j] = (f16)a[(size_t)(ks * 32 + 8 * lg + j) * NS + col];
            afr[ks] = h;
        }

        f16x4 upf = *(const f16x4*)&u16[(size_t)col * 4];

        __syncthreads();

#pragma unroll 1
        for (int s = 0; s < S_LEN; s++) {
            int cur = s & 1, nxt = cur ^ 1;

            f32x4v acca, accb;
            acca[0] = (float)upf[0]; acca[1] = (float)upf[1];
            acca[2] = (float)upf[2]; acca[3] = (float)upf[3];
            accb = (f32x4v){0.f, 0.f, 0.f, 0.f};

            {
                int sn = (s + 1 < S_LEN) ? s + 1 : S_LEN - 1;
                upf = *(const f16x4*)&u16[((size_t)sn * NS + col) * 4];
            }

            const char* sb = (const char*)Sb + cur * 4352 +
                             (lr & 3) * 1088 + lg * 16;
#pragma unroll
            for (int ks = 0; ks < 16; ks += 2) {
                f16x8 s0 = *(const f16x8*)(sb + ks * 64);
                f16x8 s1 = *(const f16x8*)(sb + ks * 64 + 64);
                acca = MFMA16(s0, afr[ks], acca);
                accb = MFMA16(s1, afr[ks + 1], accb);
            }

            // tanh + publish: X store first (fire-and-forget), then LDS
            if (lg == 0) {
                union { u64 u; f16 h[4]; } pk;
#pragma unroll
                for (int i = 0; i < 4; i++) {
                    float y = acca[i] + accb[i];
                    float e = __expf(2.0f * y);
                    float rc = __builtin_amdgcn_rcpf(e + 1.0f);
                    y = __builtin_fmaf(-2.0f, rc, 1.0f);   // tanh
                    pk.h[i] = (f16)y;
                }
                __hip_atomic_store(&X[(size_t)s * NS + col], pk.u,
                                   __ATOMIC_RELAXED, __HIP_MEMORY_SCOPE_AGENT);
#pragma unroll
                for (int i = 0; i < 4; i++)
                    Sb[nxt * 2176 + i * 544 + col] = pk.h[i];
            }

            if (s == S_LEN - 1) break;

            // data-poll gather: waves 0..5, one remote u64 per lane (simple)
            if (w < 6) {
                u64 v;
                do {
                    v = XLD(&X[(size_t)s * NS + gcol]);
                } while (v == SENT);
                union { u64 u; f16 h[4]; } pk;
                pk.u = v;
#pragma unroll
                for (int i = 0; i < 4; i++)
                    Sb[nxt * 2176 + i * 544 + gcol] = pk.h[i];
            }

            asm volatile("s_waitcnt lgkmcnt(0)" ::: "memory");
            __builtin_amdgcn_s_barrier();
            __builtin_amdgcn_sched_barrier(0);
        }
        return;
    }

    // ================= readout =================
    // XOR-swizzled LDS tiles: row stride 64 f16 (128 B), byte ^= (row&7)<<4
    char* AstB = smem;                   // [256][64] f16
    char* BwB  = smem + 256 * 64 * 2;    // [128][64] f16

    int idx = bid - NW;
    int bm = idx / 250;      // bm-major: early blocks handle early s
    int bn = idx % 250;
    int s0 = bm * 64;

    if (t == 0) {
        int sc = s0 + 56;    // canary; per-element polls below are airtight
        while (XLD(&X[(size_t)sc * NS]) == SENT)
            __builtin_amdgcn_s_sleep(16);
    }
    __syncthreads();

    int wr = w >> 1, wc = w & 1;

    f32x4v acc[4][4];
#pragma unroll
    for (int i = 0; i < 4; i++)
#pragma unroll
        for (int j = 0; j < 4; j++) acc[i][j] = (f32x4v){0.f, 0.f, 0.f, 0.f};

    for (int kc = 0; kc < 512; kc += 64) {
        __syncthreads();
        // stage A from X: plain loads, agent fallback on sentinel,
        // in-register 4x8 transpose -> 4 swizzled b128 writes
        {
            int srel = t >> 3;
            int ck = (t & 7) * 8;
            const u64* xs = &X[(size_t)(s0 + srel) * NS + kc + ck];
            u64 v[8];
#pragma unroll
            for (int j = 0; j < 8; j++) v[j] = xs[j];   // L2-cacheable
#pragma unroll
            for (int j = 0; j < 8; j++)
                while (v[j] == SENT) v[j] = XLD(&xs[j]);
#pragma unroll
            for (int b = 0; b < 4; b++) {
                f16x8 row;
#pragma unroll
                for (int j = 0; j < 8; j++) {
                    union { u64 u; f16 h[4]; } pk;
                    pk.u = v[j];
                    row[j] = pk.h[b];
                }
                int rr = srel * 4 + b;
                int byte = (rr * 128 + ck * 2) ^ ((rr & 7) << 4);
                *(f16x8*)(AstB + byte) = row;
            }
        }
        // stage B: c_w fp32 -> f16, swizzled 8B writes
#pragma unroll
        for (int q = 0; q < 4; q++) {
            int i2 = q * 512 + t;
            int row = i2 >> 4;
            int c0 = (i2 & 15) * 4;
            float4 v = *(const float4*)&cw[(size_t)(bn * 128 + row) * NS + kc + c0];
            f16x4 h;
            h[0] = (f16)v.x; h[1] = (f16)v.y; h[2] = (f16)v.z; h[3] = (f16)v.w;
            int byte = (row * 128 + c0 * 2) ^ ((row & 7) << 4);
            *(f16x4*)(BwB + byte) = h;
        }
        __syncthreads();

#pragma unroll
        for (int ks = 0; ks < 2; ks++) {
            f16x8 af[4], bf[4];
#pragma unroll
            for (int mt = 0; mt < 4; mt++) {
                int rr = wr * 64 + mt * 16 + lr;
                int byte = (rr * 128 + ks * 64 + lg * 16) ^ ((lr & 7) << 4);
                af[mt] = *(const f16x8*)(AstB + byte);
            }
#pragma unroll
            for (int vt = 0; vt < 4; vt++) {
                int rr = wc * 64 + vt * 16 + lr;
                int byte = (rr * 128 + ks * 64 + lg * 16) ^ ((lr & 7) << 4);
                bf[vt] = *(const f16x8*)(BwB + byte);
            }
#pragma unroll
            for (int mt = 0; mt < 4; mt++)
#pragma unroll
                for (int vt = 0; vt < 4; vt++)
                    acc[mt][vt] = MFMA16(af[mt], bf[vt], acc[mt][vt]);
        }
    }

    float bias[4];
#pragma unroll
    for (int vt = 0; vt < 4; vt++)
        bias[vt] = cb[bn * 128 + wc * 64 + vt * 16 + lr];

#pragma unroll
    for (int mt = 0; mt < 4; mt++) {
#pragma unroll
        for (int i = 0; i < 4; i++) {
            int m = bm * 256 + wr * 64 + mt * 16 + 4 * lg + i;
            int bb = m & 3, ss = m >> 2;
            float* orow = out + (size_t)(bb * S_LEN + ss) * NV + bn * 128 + wc * 64;
#pragma unroll
            for (int vt = 0; vt < 4; vt++)
                orow[vt * 16 + lr] = acc[mt][vt][i] + bias[vt];
        }
    }
}

// ---------------------------------------------------------------------------
extern "C" void kernel_launch(void* const* d_in, const int* in_sizes, int n_in,
                              void* d_out, int out_size, void* d_ws, size_t ws_size,
                              hipStream_t stream) {
    (void)in_sizes; (void)n_in; (void)out_size; (void)ws_size;

    const int*   x   = (const int*)d_in[0];
    const float* emb = (const float*)d_in[1];
    const float* a   = (const float*)d_in[2];
    const float* bm  = (const float*)d_in[3];
    const float* cw  = (const float*)d_in[4];
    const float* cb  = (const float*)d_in[5];
    float* out = (float*)d_out;

    char* ws = (char*)d_ws;
    f16* u16 = (f16*)(ws);
    u64* X   = (u64*)(ws + (4u << 20));
    f16* bT16 = (f16*)(ws + (8u << 20));

    hipFuncSetAttribute(reinterpret_cast<const void*>(fused_kernel),
                        hipFuncAttributeMaxDynamicSharedMemorySize,
                        FUSED_LDS);

    transpose512_f16_kernel<<<1024, 256, 0, stream>>>(bm, bT16, X);
    embu_kernel<<<64, 256, 0, stream>>>(x, emb, bT16, u16);
    fused_kernel<<<NW + 16 * 250, 512, FUSED_LDS, stream>>>(
        a, u16, cw, cb, X, out);
}

// Round 15
// 1331.907 us; speedup vs baseline: 1.1153x; 1.0195x over previous
//
#include <hip/hip_runtime.h>
#include <hip/hip_fp16.h>

typedef _Float16 f16;
typedef _Float16 f16x8 __attribute__((ext_vector_type(8)));
typedef _Float16 f16x4 __attribute__((ext_vector_type(4)));
typedef float f32x4v __attribute__((ext_vector_type(4)));
typedef unsigned long long u64;

#define S_LEN 1024
#define NS 512
#define NV 32000
#define NW 4          // scan workers (CUs); each owns 128 n-columns
#define SENT 0x7C007C007C007C00ULL   // 4x f16 +inf: unreachable for tanh output
#define FUSED_LDS 98304              // >80KB -> exactly 1 block/CU

#define MFMA16(a, b, c) __builtin_amdgcn_mfma_f32_16x16x32_f16((a), (b), (c), 0, 0, 0)

#define XLD(p) __hip_atomic_load((p), __ATOMIC_RELAXED, __HIP_MEMORY_SCOPE_AGENT)

// ---------------------------------------------------------------------------
// ws layout:
//   u16   : [1024][512][4] f16  at 0      (4 MB)   u[s][n][b]  (batch-packed)
//   X     : u64[1024][512]      at 4 MB   (4 MB)   state record + exchange
//   bT16  : [512][512]     f16  at 8 MB   (512 KB)
// ---------------------------------------------------------------------------

// transpose b -> f16, and refill X with sentinel (every launch; graph-safe)
__global__ __launch_bounds__(256) void transpose512_f16_kernel(
        const float* __restrict__ src, f16* __restrict__ dstT,
        u64* __restrict__ X) {
    int idx = blockIdx.x * 256 + threadIdx.x;   // 0..262143
    X[idx] = SENT;
    X[idx + 262144] = SENT;
    int r = idx >> 9;
    int c = idx & 511;
    dstT[c * 512 + r] = (f16)src[idx];
}

// ---------------------------------------------------------------------------
// embed + input projection: u[m][n] = sum_e emb[x[m]][e] * b[e][n], m = s*4+b
// ---------------------------------------------------------------------------
__global__ __launch_bounds__(256) void embu_kernel(
        const int* __restrict__ x, const float* __restrict__ emb,
        const f16* __restrict__ bT, f16* __restrict__ u16) {
    __shared__ f16 embA[64 * 40];
    __shared__ f16 Bt[512 * 40];
    __shared__ int xi[64];

    int t = threadIdx.x;
    int wg = blockIdx.x;
    if (t < 64) {
        int m = wg * 64 + t;
        int bb = m & 3, ss = m >> 2;
        xi[t] = x[bb * S_LEN + ss];
    }
    __syncthreads();

    int wv = t >> 6, l = t & 63, lr = l & 15, lg = l >> 4;

    f32x4v acc[32];
#pragma unroll
    for (int i = 0; i < 32; i++) acc[i] = (f32x4v){0.f, 0.f, 0.f, 0.f};

    for (int kc = 0; kc < 512; kc += 32) {
        __syncthreads();
        {
            int tk = t >> 2, c0 = (t & 3) * 8;
            const float* src = emb + (size_t)xi[tk] * NS + kc + c0;
            float4 v0 = *(const float4*)src;
            float4 v1 = *(const float4*)(src + 4);
            f16x8 h;
            h[0] = (f16)v0.x; h[1] = (f16)v0.y; h[2] = (f16)v0.z; h[3] = (f16)v0.w;
            h[4] = (f16)v1.x; h[5] = (f16)v1.y; h[6] = (f16)v1.z; h[7] = (f16)v1.w;
            *(f16x8*)&embA[tk * 40 + c0] = h;
        }
        {
            int c0 = (t & 3) * 8;
            int n0 = t >> 2;
#pragma unroll
            for (int rr = 0; rr < 8; rr++) {
                int n = rr * 64 + n0;
                f16x8 v = *(const f16x8*)&bT[n * 512 + kc + c0];
                *(f16x8*)&Bt[n * 40 + c0] = v;
            }
        }
        __syncthreads();

        f16x8 af = *(const f16x8*)&embA[(wv * 16 + lr) * 40 + 8 * lg];
#pragma unroll
        for (int vt = 0; vt < 32; vt++) {
            f16x8 bf = *(const f16x8*)&Bt[(vt * 16 + lr) * 40 + 8 * lg];
            acc[vt] = MFMA16(af, bf, acc[vt]);
        }
    }

    int m0 = wg * 64 + wv * 16 + 4 * lg;
    int ss = m0 >> 2;
#pragma unroll
    for (int vt = 0; vt < 32; vt++) {
        int n = vt * 16 + lr;
        f16x4 h;
#pragma unroll
        for (int i = 0; i < 4; i++) h[i] = (f16)acc[vt][i];
        *(f16x4*)&u16[((size_t)ss * NS + n) * 4] = h;
    }
}

// ---------------------------------------------------------------------------
// FUSED scan + readout (R7/R11 structure — empirical optimum).
//   blocks 0..3     : scan (4 CUs, col-partitioned, data-poll exchange via X)
//   blocks 4..4003  : readout tiles; canary gate; A staged from X with plain
//                     (L2-cacheable) loads + agent-scope fallback on SENT;
//                     register-transposed b128 LDS writes.
// 96 KB dynamic LDS -> 1 block/CU.
// ---------------------------------------------------------------------------
__global__ __launch_bounds__(512) void fused_kernel(
        const float* __restrict__ a, const f16* __restrict__ u16,
        const float* __restrict__ cw, const float* __restrict__ cb,
        u64* __restrict__ X, float* __restrict__ out) {
    extern __shared__ char smem[];
    int t = threadIdx.x;
    int bid = blockIdx.x;
    int w = t >> 6, l = t & 63, lr = l & 15, lg = l >> 4;

    if (bid < NW) {
        // ================= scan =================
        f16* Sb = (f16*)smem;               // [2][4][544] f16
        int r = bid;
        int col = r * 128 + w * 16 + lr;

        int gcol = -1;
        if (w < 6) {
            int cwk = w + (w >= 2 * r ? 2 : 0);   // skip own chunks {2r,2r+1}
            gcol = cwk * 64 + l;
        }

        for (int i = t; i < 2 * 4 * 544; i += 512) Sb[i] = (f16)0.f;

        // stationary A fragments (64 VGPR/lane)
        f16x8 afr[16];
#pragma unroll
        for (int ks = 0; ks < 16; ks++) {
            f16x8 h;
#pragma unroll
            for (int j = 0; j < 8; j++)
                h[j] = (f16)a[(size_t)(ks * 32 + 8 * lg + j) * NS + col];
            afr[ks] = h;
        }

        f16x4 upf = *(const f16x4*)&u16[(size_t)col * 4];

        __syncthreads();

#pragma unroll 1
        for (int s = 0; s < S_LEN; s++) {
            int cur = s & 1, nxt = cur ^ 1;

            f32x4v acca, accb;
            acca[0] = (float)upf[0]; acca[1] = (float)upf[1];
            acca[2] = (float)upf[2]; acca[3] = (float)upf[3];
            accb = (f32x4v){0.f, 0.f, 0.f, 0.f};

            {
                int sn = (s + 1 < S_LEN) ? s + 1 : S_LEN - 1;
                upf = *(const f16x4*)&u16[((size_t)sn * NS + col) * 4];
            }

            const char* sb = (const char*)Sb + cur * 4352 +
                             (lr & 3) * 1088 + lg * 16;
#pragma unroll
            for (int ks = 0; ks < 16; ks += 2) {
                f16x8 s0 = *(const f16x8*)(sb + ks * 64);
                f16x8 s1 = *(const f16x8*)(sb + ks * 64 + 64);
                acca = MFMA16(s0, afr[ks], acca);
                accb = MFMA16(s1, afr[ks + 1], accb);
            }

            // tanh + publish: X store first (fire-and-forget), then LDS
            if (lg == 0) {
                union { u64 u; f16 h[4]; } pk;
#pragma unroll
                for (int i = 0; i < 4; i++) {
                    float y = acca[i] + accb[i];
                    float e = __expf(2.0f * y);
                    float rc = __builtin_amdgcn_rcpf(e + 1.0f);
                    y = __builtin_fmaf(-2.0f, rc, 1.0f);   // tanh
                    pk.h[i] = (f16)y;
                }
                __hip_atomic_store(&X[(size_t)s * NS + col], pk.u,
                                   __ATOMIC_RELAXED, __HIP_MEMORY_SCOPE_AGENT);
#pragma unroll
                for (int i = 0; i < 4; i++)
                    Sb[nxt * 2176 + i * 544 + col] = pk.h[i];
            }

            if (s == S_LEN - 1) break;

            // data-poll gather: waves 0..5, one remote u64 per lane
            if (w < 6) {
                u64 v;
                do {
                    v = XLD(&X[(size_t)s * NS + gcol]);
                } while (v == SENT);
                union { u64 u; f16 h[4]; } pk;
                pk.u = v;
#pragma unroll
                for (int i = 0; i < 4; i++)
                    Sb[nxt * 2176 + i * 544 + gcol] = pk.h[i];
            }

            asm volatile("s_waitcnt lgkmcnt(0)" ::: "memory");
            __builtin_amdgcn_s_barrier();
            __builtin_amdgcn_sched_barrier(0);
        }
        return;
    }

    // ================= readout =================
    f16* Ast = (f16*)smem;                 // [256][72]
    f16* Bw = (f16*)(smem + 256 * 72 * 2); // [128][72]

    int idx = bid - NW;
    int bm = idx / 250;      // bm-major: early blocks handle early s
    int bn = idx % 250;
    int s0 = bm * 64;

    if (t == 0) {
        int sc = (bm == 15) ? (S_LEN - 1) : (s0 + 64);
        while (XLD(&X[(size_t)sc * NS]) == SENT)
            __builtin_amdgcn_s_sleep(16);
    }
    __syncthreads();

    int wr = w >> 1, wc = w & 1;

    f32x4v acc[4][4];
#pragma unroll
    for (int i = 0; i < 4; i++)
#pragma unroll
        for (int j = 0; j < 4; j++) acc[i][j] = (f32x4v){0.f, 0.f, 0.f, 0.f};

    for (int kc = 0; kc < 512; kc += 64) {
        __syncthreads();
        // stage A from X: plain (cacheable) loads; agent-scope fallback on
        // sentinel; in-register 4x8 transpose -> 4 ds_write_b128 per thread
        {
            int srel = t >> 3;
            int ck = (t & 7) * 8;
            const u64* xs = &X[(size_t)(s0 + srel) * NS + kc + ck];
            u64 v[8];
#pragma unroll
            for (int j = 0; j < 8; j++) v[j] = xs[j];   // plain, L2-cacheable
#pragma unroll
            for (int j = 0; j < 8; j++)
                while (v[j] == SENT)
                    v[j] = XLD(&xs[j]);
#pragma unroll
            for (int b = 0; b < 4; b++) {
                f16x8 row;
#pragma unroll
                for (int j = 0; j < 8; j++) {
                    union { u64 u; f16 h[4]; } pk;
                    pk.u = v[j];
                    row[j] = pk.h[b];
                }
                *(f16x8*)&Ast[(srel * 4 + b) * 72 + ck] = row;
            }
        }
#pragma unroll
        for (int q = 0; q < 4; q++) {
            int i2 = q * 512 + t;
            int row = i2 >> 4;
            int c0 = (i2 & 15) * 4;
            float4 v = *(const float4*)&cw[(size_t)(bn * 128 + row) * NS + kc + c0];
            f16x4 h;
            h[0] = (f16)v.x; h[1] = (f16)v.y; h[2] = (f16)v.z; h[3] = (f16)v.w;
            *(f16x4*)&Bw[row * 72 + c0] = h;
        }
        __syncthreads();

#pragma unroll
        for (int ks = 0; ks < 2; ks++) {
            f16x8 af[4], bf[4];
#pragma unroll
            for (int mt = 0; mt < 4; mt++)
                af[mt] = *(const f16x8*)&Ast[(wr * 64 + mt * 16 + lr) * 72 +
                                             ks * 32 + 8 * lg];
#pragma unroll
            for (int vt = 0; vt < 4; vt++)
                bf[vt] = *(const f16x8*)&Bw[(wc * 64 + vt * 16 + lr) * 72 +
                                            ks * 32 + 8 * lg];
#pragma unroll
            for (int mt = 0; mt < 4; mt++)
#pragma unroll
                for (int vt = 0; vt < 4; vt++)
                    acc[mt][vt] = MFMA16(af[mt], bf[vt], acc[mt][vt]);
        }
    }

    float bias[4];
#pragma unroll
    for (int vt = 0; vt < 4; vt++)
        bias[vt] = cb[bn * 128 + wc * 64 + vt * 16 + lr];

#pragma unroll
    for (int mt = 0; mt < 4; mt++) {
#pragma unroll
        for (int i = 0; i < 4; i++) {
            int m = bm * 256 + wr * 64 + mt * 16 + 4 * lg + i;
            int bb = m & 3, ss = m >> 2;
            float* orow = out + (size_t)(bb * S_LEN + ss) * NV + bn * 128 + wc * 64;
#pragma unroll
            for (int vt = 0; vt < 4; vt++)
                orow[vt * 16 + lr] = acc[mt][vt][i] + bias[vt];
        }
    }
}

// ---------------------------------------------------------------------------
extern "C" void kernel_launch(void* const* d_in, const int* in_sizes, int n_in,
                              void* d_out, int out_size, void* d_ws, size_t ws_size,
                              hipStream_t stream) {
    (void)in_sizes; (void)n_in; (void)out_size; (void)ws_size;

    const int*   x   = (const int*)d_in[0];
    const float* emb = (const float*)d_in[1];
    const float* a   = (const float*)d_in[2];
    const float* bm  = (const float*)d_in[3];
    const float* cw  = (const float*)d_in[4];
    const float* cb  = (const float*)d_in[5];
    float* out = (float*)d_out;

    char* ws = (char*)d_ws;
    f16* u16 = (f16*)(ws);
    u64* X   = (u64*)(ws + (4u << 20));
    f16* bT16 = (f16*)(ws + (8u << 20));

    hipFuncSetAttribute(reinterpret_cast<const void*>(fused_kernel),
                        hipFuncAttributeMaxDynamicSharedMemorySize,
                        FUSED_LDS);

    transpose512_f16_kernel<<<1024, 256, 0, stream>>>(bm, bT16, X);
    embu_kernel<<<64, 256, 0, stream>>>(x, emb, bT16, u16);
    fused_kernel<<<NW + 16 * 250, 512, FUSED_LDS, stream>>>(
        a, u16, cw, cb, X, out);
}